// Round 11
// baseline (78.763 us; speedup 1.0000x reference)
//
#include <hip/hip_runtime.h>

typedef __attribute__((ext_vector_type(8))) short bf16x8;
typedef __attribute__((ext_vector_type(4))) float f32x4;

#define SP 8192
#define INF 256
#define HID 64
#define NEG 0.2f

__device__ __forceinline__ unsigned bf16r(float x) {
    unsigned u = __float_as_uint(x);
    return (u + 0x7FFFu + ((u >> 16) & 1u)) >> 16;
}

// ---------------- Kernel A: projection + LeakyReLU + sumsq + bf16 hi/lo split
// F rows 0..8191 = input1, 8192..16383 = input2. Output in MFMA-fragment order:
//   element (row, k) -> plane p (hi/lo), flat = ((R*2+s)*64 + lfr)*8 + (k&7)
//   R = row>>4, s = k>>5, lfr = (row&15) | (((k>>3)&3)<<4)
__global__ __launch_bounds__(256) void proj_kernel(
    const float* __restrict__ in1, const float* __restrict__ in2,
    const float* __restrict__ w,
    unsigned short* __restrict__ Fhi, unsigned short* __restrict__ Flo,
    float* __restrict__ SQ)
{
    __shared__ float wl[INF * HID];  // 64 KB, [k][h]
    int tid = threadIdx.x;
    {
        const float4* w4 = (const float4*)w;
        float4* wl4 = (float4*)wl;
        #pragma unroll
        for (int i = 0; i < 16; i++) wl4[tid + 256 * i] = w4[tid + 256 * i];
    }
    __syncthreads();

    int blk = blockIdx.x;                       // 512 blocks, 32 rows each
    const float* rowbase = ((blk < 256) ? in1 : in2) + (long)(blk & 255) * 32 * INF;
    int c0 = (tid & 15) * 4;                    // 4 consecutive output cols
    int r0 = (tid >> 4) * 2;                    // 2 consecutive rows

    float acc[2][4];
    #pragma unroll
    for (int i = 0; i < 2; i++)
        #pragma unroll
        for (int j = 0; j < 4; j++) acc[i][j] = 0.f;

    // software-pipelined k loop: prefetch next iteration's A rows
    float4 a[2], an[2];
    #pragma unroll
    for (int i = 0; i < 2; i++) a[i] = *(const float4*)(rowbase + (r0 + i) * INF);
    for (int k = 0; k < INF; k += 4) {
        if (k < INF - 4) {
            #pragma unroll
            for (int i = 0; i < 2; i++)
                an[i] = *(const float4*)(rowbase + (r0 + i) * INF + k + 4);
        }
        #pragma unroll
        for (int kk = 0; kk < 4; kk++) {
            float4 wv = *(const float4*)(wl + (k + kk) * HID + c0);
            #pragma unroll
            for (int i = 0; i < 2; i++) {
                float av = (kk == 0) ? a[i].x : (kk == 1) ? a[i].y
                         : (kk == 2) ? a[i].z : a[i].w;
                acc[i][0] = fmaf(av, wv.x, acc[i][0]);
                acc[i][1] = fmaf(av, wv.y, acc[i][1]);
                acc[i][2] = fmaf(av, wv.z, acc[i][2]);
                acc[i][3] = fmaf(av, wv.w, acc[i][3]);
            }
        }
        #pragma unroll
        for (int i = 0; i < 2; i++) a[i] = an[i];
    }

    // LeakyReLU + per-row sum of squares (partial over this thread's 4 cols)
    float ss[2];
    #pragma unroll
    for (int i = 0; i < 2; i++) {
        ss[i] = 0.f;
        #pragma unroll
        for (int j = 0; j < 4; j++) {
            float v = acc[i][j];
            v = (v > 0.f) ? v : NEG * v;
            acc[i][j] = v;
            ss[i] = fmaf(v, v, ss[i]);
        }
    }
    #pragma unroll
    for (int m = 1; m < 16; m <<= 1) {
        #pragma unroll
        for (int i = 0; i < 2; i++) ss[i] += __shfl_xor(ss[i], m, 64);
    }
    int growb = blk * 32 + r0;
    if ((tid & 15) < 2) {
        float sv = ((tid & 15) == 0) ? ss[0] : ss[1];
        SQ[growb + (tid & 15)] = sv;
    }

    // bf16 hi/lo split, store in fragment order
    int s  = c0 >> 5;
    int g  = (c0 >> 3) & 3;
    int jb = c0 & 7;                 // 0 or 4
    #pragma unroll
    for (int i = 0; i < 2; i++) {
        int grow = growb + i;
        int R = grow >> 4;
        int lfr = (grow & 15) | (g << 4);
        long fi = ((long)((R * 2 + s) * 64 + lfr)) * 8 + jb;
        ushort4 hv, lv;
        unsigned short* ph = (unsigned short*)&hv;
        unsigned short* pl = (unsigned short*)&lv;
        #pragma unroll
        for (int j = 0; j < 4; j++) {
            float v = acc[i][j];
            unsigned hb = bf16r(v);
            float hf = __uint_as_float(hb << 16);
            unsigned lb = bf16r(v - hf);
            ph[j] = (unsigned short)hb;
            pl[j] = (unsigned short)lb;
        }
        *(ushort4*)(Fhi + fi) = hv;
        *(ushort4*)(Flo + fi) = lv;
    }
}

// light barrier: orders LDS traffic only (lgkmcnt), does NOT drain the
// global-store queue (vmcnt) like __syncthreads would.
__device__ __forceinline__ void lds_barrier() {
    asm volatile("s_waitcnt lgkmcnt(0)" ::: "memory");
    __builtin_amdgcn_s_barrier();
    asm volatile("" ::: "memory");
}

// ---------------- Kernel B: pairwise, 256x256 tiles, bf16x3 MFMA,
// LDS-transposed epilogue, store-in-flight pipelining, and NON-TEMPORAL
// full-line stores: each store instruction covers 1 KB contiguous (full
// 128B lines), so nt write-combines cleanly and the 256 MB store stream
// does NOT allocate in L2 -- keeping the A fragment panels (2 MB/XCD
// working set) L2-resident so per-phase A re-reads (256 MB demand) stay
// on-XCD instead of thrashing out to L3/fabric.
__global__ __launch_bounds__(256, 4) void pair_kernel(
    const unsigned short* __restrict__ Fhi, const unsigned short* __restrict__ Flo,
    const float* __restrict__ SQ, float* __restrict__ out)
{
    __shared__ float lds[2][16][256];   // 32 KB double-buffered result tile

    int bid = blockIdx.x;
    int xcd = bid & 7;
    int kk = bid >> 3;                // 0..127 within XCD
    int tc = xcd * 4 + (kk >> 5);     // 4 tile-columns per XCD
    int tr = kk & 31;                 // rows swept fastest (B-panel reuse)
    int lane = threadIdx.x & 63;
    int wave = threadIdx.x >> 6;
    int row0 = tr * 256;
    int col0 = tc * 256;              // block col base
    int wcol0 = col0 + wave * 64;     // this wave's compute cols

    const bf16x8* FhiV = (const bf16x8*)Fhi;
    const bf16x8* FloV = (const bf16x8*)Flo;

    int RA0 = tr * 16;
    int RB0 = 512 + tc * 16 + wave * 4;   // f2 region starts at F row 8192 -> R=512

    // col (f2) fragments: 4 n x 2 s, both planes (64 VGPRs), held all phases
    bf16x8 bh[2][4], bl[2][4];
    #pragma unroll
    for (int s = 0; s < 2; s++)
        #pragma unroll
        for (int n = 0; n < 4; n++) {
            int fi = ((RB0 + n) * 2 + s) * 64 + lane;
            bh[s][n] = FhiV[fi];
            bl[s][n] = FloV[fi];
        }

    // pre-scale squared norms by log2e^2 so sqrt() yields dist*log2e directly
    const float C2 = 2.081368898419084f;      // (log2 e)^2
    float sqb[4];
    #pragma unroll
    for (int n = 0; n < 4; n++) sqb[n] = SQ[SP + wcol0 + 16 * n + (lane & 15)] * C2;

    int rbase = (lane >> 4) * 4;      // output row group within 16
    int swz = (lane & 16);            // == (row&4)<<2 for rows rbase..rbase+3
    int start = (bid * 5) & 15;       // phase skew (de-convoy)
    int mprev = 0;                    // phase id of data waiting in buf^1

    #pragma unroll 1
    for (int mi = 0; mi < 16; mi++) {
        int m = (mi + start) & 15;
        int buf = mi & 1;

        // 1. issue this phase's row (f1) fragment loads FIRST (4 x dwordx4)
        bf16x8 ah[2], al[2];
        #pragma unroll
        for (int s = 0; s < 2; s++) {
            int fi = ((RA0 + m) * 2 + s) * 64 + lane;
            ah[s] = FhiV[fi];
            al[s] = FloV[fi];
        }

        // 2. trailing store of phase mi-1 from buf^1 (ds_read -> nt global)
        if (mi > 0) {
            #pragma unroll
            for (int j = 0; j < 4; j++) {
                int r = wave * 4 + j;
                int rs = (r & 4) << 2;
                f32x4 vv = *(const f32x4*)&lds[buf ^ 1][r][(lane * 4) ^ rs];
                __builtin_nontemporal_store(vv,
                    (f32x4*)(out + (long)(row0 + 16 * mprev + r) * SP + col0 + lane * 4));
            }
        }

        // 3. MFMA (waits only on the A loads; issued before the stores, so
        //    the FIFO vmcnt wait does not drain the stores)
        f32x4 acc[4];
        #pragma unroll
        for (int n = 0; n < 4; n++) acc[n] = (f32x4){0.f, 0.f, 0.f, 0.f};
        #pragma unroll
        for (int s = 0; s < 2; s++)
            #pragma unroll
            for (int n = 0; n < 4; n++) {
                acc[n] = __builtin_amdgcn_mfma_f32_16x16x32_bf16(ah[s], bh[s][n], acc[n], 0, 0, 0);
                acc[n] = __builtin_amdgcn_mfma_f32_16x16x32_bf16(ah[s], bl[s][n], acc[n], 0, 0, 0);
                acc[n] = __builtin_amdgcn_mfma_f32_16x16x32_bf16(al[s], bh[s][n], acc[n], 0, 0, 0);
            }

        // 4. epilogue math -> LDS buf (swizzled)
        // q = (sq1+sq2-2dot)*log2e^2; d' = sqrt(q) = dist*log2e
        // y = exp2(-d') = e^-dist; sigmoid(-dist) ~= y - y^2 (err <= y^3 <= 4.5e-6)
        float4 t = *(const float4*)(SQ + row0 + 16 * m + rbase);
        float sa[4] = {t.x * C2, t.y * C2, t.z * C2, t.w * C2};
        #pragma unroll
        for (int n = 0; n < 4; n++) {
            int colb = (wave * 64 + 16 * n + (lane & 15)) ^ swz;
            #pragma unroll
            for (int v = 0; v < 4; v++) {
                float q = fmaf(acc[n][v], -2.f * C2, sa[v] + sqb[n]);
                q = fmaxf(q, 0.f);
                float d = __builtin_amdgcn_sqrtf(q);        // dist * log2e
                float y = __builtin_amdgcn_exp2f(-d);       // e^-dist
                lds[buf][rbase + v][colb] = fmaf(-y, y, y); // y - y^2
            }
        }

        // 5. lgkm-only barrier: hand buf to the store phase of iter mi+1
        lds_barrier();
        mprev = m;
    }

    // tail: store the last phase's tile
    #pragma unroll
    for (int j = 0; j < 4; j++) {
        int r = wave * 4 + j;
        int rs = (r & 4) << 2;
        f32x4 vv = *(const f32x4*)&lds[1][r][(lane * 4) ^ rs];
        __builtin_nontemporal_store(vv,
            (f32x4*)(out + (long)(row0 + 16 * mprev + r) * SP + col0 + lane * 4));
    }
}

extern "C" void kernel_launch(void* const* d_in, const int* in_sizes, int n_in,
                              void* d_out, int out_size, void* d_ws, size_t ws_size,
                              hipStream_t stream)
{
    const float* in1 = (const float*)d_in[0];
    const float* in2 = (const float*)d_in[1];
    const float* w   = (const float*)d_in[2];
    float* out = (float*)d_out;
    char* ws = (char*)d_ws;
    unsigned short* Fhi = (unsigned short*)ws;                       // 2 MB
    unsigned short* Flo = (unsigned short*)(ws + 2u * 1024 * 1024);  // 2 MB
    float* SQ = (float*)(ws + 4u * 1024 * 1024);                     // 64 KB

    hipLaunchKernelGGL(proj_kernel, dim3(512), dim3(256), 0, stream,
                       in1, in2, w, Fhi, Flo, SQ);
    hipLaunchKernelGGL(pair_kernel, dim3(1024), dim3(256), 0, stream,
                       Fhi, Flo, SQ, out);
}

// Round 13
// 73.765 us; speedup vs baseline: 1.0678x; 1.0678x over previous
//
#include <hip/hip_runtime.h>

typedef __attribute__((ext_vector_type(8))) short bf16x8;
typedef __attribute__((ext_vector_type(4))) float f32x4;

#define SP 8192
#define INF 256
#define HID 64
#define NEG 0.2f

__device__ __forceinline__ unsigned bf16r(float x) {
    unsigned u = __float_as_uint(x);
    return (u + 0x7FFFu + ((u >> 16) & 1u)) >> 16;
}

// ---------------- Kernel A: projection + LeakyReLU + sumsq + bf16 hi/lo split
// 1024 blocks x 16 rows, 32 KB LDS -> 4 blocks/CU (4 waves/SIMD TLP hides the
// streamed A-row latency; old 512-block version was 2/CU and latency-exposed).
// w staged in two 32 KB halves. F rows 0..8191 = input1, 8192..16383 = input2,
// stored in MFMA-fragment order:
//   element (row,k) -> flat = ((R*2+s)*64 + lfr)*8 + (k&7)
//   R=row>>4, s=k>>5, lfr=(row&15)|(((k>>3)&3)<<4)
__global__ __launch_bounds__(256, 4) void proj_kernel(
    const float* __restrict__ in1, const float* __restrict__ in2,
    const float* __restrict__ w,
    unsigned short* __restrict__ Fhi, unsigned short* __restrict__ Flo,
    float* __restrict__ SQ)
{
    __shared__ float sbuf[128 * HID];   // 32 KB: one half of w

    int bid = blockIdx.x;
    int tid = threadIdx.x;
    const float* rowbase = ((bid < 512) ? in1 : in2) + (long)(bid & 511) * 16 * INF;
    int r  = tid >> 4;          // 16 rows per block, 16 threads per row
    int c0 = (tid & 15) * 4;    // 4 consecutive output cols per thread

    float acc[4] = {0.f, 0.f, 0.f, 0.f};
    #pragma unroll 1
    for (int half = 0; half < 2; half++) {
        // stage w[half*128 .. +128) : 128 x 64 floats = 32 KB
        const float4* w4 = (const float4*)(w + half * 128 * HID);
        float4* s4 = (float4*)sbuf;
        #pragma unroll
        for (int i = 0; i < 8; i++) s4[tid + 256 * i] = w4[tid + 256 * i];
        __syncthreads();

        const float* arow = rowbase + r * INF + half * 128;
        #pragma unroll 4
        for (int k = 0; k < 128; k += 4) {
            float4 av = *(const float4*)(arow + k);
            #pragma unroll
            for (int kk = 0; kk < 4; kk++) {
                float a = (kk == 0) ? av.x : (kk == 1) ? av.y
                        : (kk == 2) ? av.z : av.w;
                float4 wv = *(const float4*)(sbuf + (k + kk) * HID + c0);
                acc[0] = fmaf(a, wv.x, acc[0]);
                acc[1] = fmaf(a, wv.y, acc[1]);
                acc[2] = fmaf(a, wv.z, acc[2]);
                acc[3] = fmaf(a, wv.w, acc[3]);
            }
        }
        __syncthreads();   // protect sbuf before restaging
    }

    // LeakyReLU + row sum of squares (reduce over the row's 16 lanes)
    float ss = 0.f;
    #pragma unroll
    for (int j = 0; j < 4; j++) {
        float v = acc[j];
        v = (v > 0.f) ? v : NEG * v;
        acc[j] = v;
        ss = fmaf(v, v, ss);
    }
    #pragma unroll
    for (int msk = 1; msk < 16; msk <<= 1) ss += __shfl_xor(ss, msk, 64);

    int grow = bid * 16 + r;
    if ((tid & 15) == 0) SQ[grow] = ss;

    // bf16 hi/lo split -> fragment order
    int s  = c0 >> 5;
    int g  = (c0 >> 3) & 3;
    int jb = c0 & 7;
    int R   = grow >> 4;                // == bid
    int lfr = (grow & 15) | (g << 4);   // == r | (g<<4)
    long fi = ((long)((R * 2 + s) * 64 + lfr)) * 8 + jb;
    ushort4 hv, lv;
    unsigned short* ph = (unsigned short*)&hv;
    unsigned short* pl = (unsigned short*)&lv;
    #pragma unroll
    for (int j = 0; j < 4; j++) {
        float v = acc[j];
        unsigned hb = bf16r(v);
        float hf = __uint_as_float(hb << 16);
        unsigned lb = bf16r(v - hf);
        ph[j] = (unsigned short)hb;
        pl[j] = (unsigned short)lb;
    }
    *(ushort4*)(Fhi + fi) = hv;
    *(ushort4*)(Flo + fi) = lv;
}

// light barrier: orders LDS traffic only (lgkmcnt), does NOT drain the
// global-store queue (vmcnt) like __syncthreads would.
__device__ __forceinline__ void lds_barrier() {
    asm volatile("s_waitcnt lgkmcnt(0)" ::: "memory");
    __builtin_amdgcn_s_barrier();
    asm volatile("" ::: "memory");
}

// ---------------- Kernel B: pairwise, 256x256 tiles, bf16x3 MFMA,
// LDS-transposed epilogue, store-in-flight pipelining (lgkm-only barriers),
// 1 KB-contiguous full-line stores, per-XCD column-major swizzle, phase skew.
// (R9-verified structure, best measured.)
__global__ __launch_bounds__(256, 4) void pair_kernel(
    const unsigned short* __restrict__ Fhi, const unsigned short* __restrict__ Flo,
    const float* __restrict__ SQ, float* __restrict__ out)
{
    __shared__ float lds[2][16][256];   // 32 KB double-buffered result tile

    int bid = blockIdx.x;
    int xcd = bid & 7;
    int kk = bid >> 3;                // 0..127 within XCD
    int tc = xcd * 4 + (kk >> 5);     // 4 tile-columns per XCD
    int tr = kk & 31;                 // rows swept fastest (B-panel reuse)
    int lane = threadIdx.x & 63;
    int wave = threadIdx.x >> 6;
    int row0 = tr * 256;
    int col0 = tc * 256;              // block col base
    int wcol0 = col0 + wave * 64;     // this wave's compute cols

    const bf16x8* FhiV = (const bf16x8*)Fhi;
    const bf16x8* FloV = (const bf16x8*)Flo;

    int RA0 = tr * 16;
    int RB0 = 512 + tc * 16 + wave * 4;   // f2 region starts at F row 8192 -> R=512

    // col (f2) fragments: 4 n x 2 s, both planes (64 VGPRs), held all phases
    bf16x8 bh[2][4], bl[2][4];
    #pragma unroll
    for (int s = 0; s < 2; s++)
        #pragma unroll
        for (int n = 0; n < 4; n++) {
            int fi = ((RB0 + n) * 2 + s) * 64 + lane;
            bh[s][n] = FhiV[fi];
            bl[s][n] = FloV[fi];
        }

    // pre-scale squared norms by log2e^2 so sqrt() yields dist*log2e directly
    const float C2 = 2.081368898419084f;      // (log2 e)^2
    float sqb[4];
    #pragma unroll
    for (int n = 0; n < 4; n++) sqb[n] = SQ[SP + wcol0 + 16 * n + (lane & 15)] * C2;

    int rbase = (lane >> 4) * 4;      // output row group within 16
    int swz = (lane & 16);            // == (row&4)<<2 for rows rbase..rbase+3
    int start = (bid * 5) & 15;       // phase skew (de-convoy)
    int mprev = 0;                    // phase id of data waiting in buf^1

    #pragma unroll 1
    for (int mi = 0; mi < 16; mi++) {
        int m = (mi + start) & 15;
        int buf = mi & 1;

        // 1. issue this phase's row (f1) fragment loads FIRST (4 x dwordx4)
        bf16x8 ah[2], al[2];
        #pragma unroll
        for (int s = 0; s < 2; s++) {
            int fi = ((RA0 + m) * 2 + s) * 64 + lane;
            ah[s] = FhiV[fi];
            al[s] = FloV[fi];
        }

        // 2. trailing store of phase mi-1 from buf^1 (1 KB contiguous)
        if (mi > 0) {
            #pragma unroll
            for (int j = 0; j < 4; j++) {
                int r = wave * 4 + j;
                int rs = (r & 4) << 2;
                f32x4 vv = *(const f32x4*)&lds[buf ^ 1][r][(lane * 4) ^ rs];
                *(f32x4*)(out + (long)(row0 + 16 * mprev + r) * SP + col0 + lane * 4) = vv;
            }
        }

        // 3. MFMA (waits only on the A loads; issued before the stores, so
        //    the FIFO vmcnt wait does not drain the stores)
        f32x4 acc[4];
        #pragma unroll
        for (int n = 0; n < 4; n++) acc[n] = (f32x4){0.f, 0.f, 0.f, 0.f};
        #pragma unroll
        for (int s = 0; s < 2; s++)
            #pragma unroll
            for (int n = 0; n < 4; n++) {
                acc[n] = __builtin_amdgcn_mfma_f32_16x16x32_bf16(ah[s], bh[s][n], acc[n], 0, 0, 0);
                acc[n] = __builtin_amdgcn_mfma_f32_16x16x32_bf16(ah[s], bl[s][n], acc[n], 0, 0, 0);
                acc[n] = __builtin_amdgcn_mfma_f32_16x16x32_bf16(al[s], bh[s][n], acc[n], 0, 0, 0);
            }

        // 4. epilogue -> LDS buf (swizzled)
        // q=(sq1+sq2-2dot)*log2e^2; d'=sqrt(q)=dist*log2e
        // y=exp2(-d')=e^-dist; sigmoid(-dist) ~= y-y^2 (err<=y^3<=4.5e-6)
        float4 t = *(const float4*)(SQ + row0 + 16 * m + rbase);
        float sa[4] = {t.x * C2, t.y * C2, t.z * C2, t.w * C2};
        #pragma unroll
        for (int n = 0; n < 4; n++) {
            int colb = (wave * 64 + 16 * n + (lane & 15)) ^ swz;
            #pragma unroll
            for (int v = 0; v < 4; v++) {
                float q = fmaf(acc[n][v], -2.f * C2, sa[v] + sqb[n]);
                q = fmaxf(q, 0.f);
                float d = __builtin_amdgcn_sqrtf(q);        // dist * log2e
                float y = __builtin_amdgcn_exp2f(-d);       // e^-dist
                lds[buf][rbase + v][colb] = fmaf(-y, y, y); // y - y^2
            }
        }

        // 5. lgkm-only barrier: hand buf to the store of iter mi+1
        lds_barrier();
        mprev = m;
    }

    // tail: store the last phase's tile (buf index 1)
    #pragma unroll
    for (int j = 0; j < 4; j++) {
        int r = wave * 4 + j;
        int rs = (r & 4) << 2;
        f32x4 vv = *(const f32x4*)&lds[1][r][(lane * 4) ^ rs];
        *(f32x4*)(out + (long)(row0 + 16 * mprev + r) * SP + col0 + lane * 4) = vv;
    }
}

extern "C" void kernel_launch(void* const* d_in, const int* in_sizes, int n_in,
                              void* d_out, int out_size, void* d_ws, size_t ws_size,
                              hipStream_t stream)
{
    const float* in1 = (const float*)d_in[0];
    const float* in2 = (const float*)d_in[1];
    const float* w   = (const float*)d_in[2];
    float* out = (float*)d_out;
    char* ws = (char*)d_ws;
    unsigned short* Fhi = (unsigned short*)ws;                       // 2 MB
    unsigned short* Flo = (unsigned short*)(ws + 2u * 1024 * 1024);  // 2 MB
    float* SQ = (float*)(ws + 4u * 1024 * 1024);                     // 64 KB

    hipLaunchKernelGGL(proj_kernel, dim3(1024), dim3(256), 0, stream,
                       in1, in2, w, Fhi, Flo, SQ);
    hipLaunchKernelGGL(pair_kernel, dim3(1024), dim3(256), 0, stream,
                       Fhi, Flo, SQ, out);
}